// Round 12
// baseline (476.049 us; speedup 1.0000x reference)
//
#include <hip/hip_runtime.h>

#define N_NODES 16384
#define KDIM    16384
#define E_EDGES 524288
#define H1DIM   200
#define H2DIM   8
#define BNP     256     // padded H1

#define BM 128
#define BK 32
#define KSPLIT 4
#define KLEN 4096       // KDIM / KSPLIT
#define NT 128          // KLEN / BK

typedef __attribute__((ext_vector_type(8))) short bf16x8;
typedef __attribute__((ext_vector_type(4))) float fx4;
typedef __attribute__((ext_vector_type(4))) unsigned int ux4;
typedef __attribute__((ext_vector_type(2))) unsigned int ux2;

__device__ __forceinline__ unsigned short f2bf(float f) {
  unsigned int u = __builtin_bit_cast(unsigned int, f);
  return (unsigned short)((u + 0x7FFFu + ((u >> 16) & 1u)) >> 16);  // RNE
}
__device__ __forceinline__ unsigned int pk2(float a, float b) {
  return (unsigned int)f2bf(a) | ((unsigned int)f2bf(b) << 16);
}
__device__ __forceinline__ float bf2f(unsigned int u) {
  return __builtin_bit_cast(float, u << 16);
}

// ---------------- degree / CSR build (R5 verbatim) ----------------

__global__ void k_degcnt(const int* __restrict__ ei, const float* __restrict__ ew,
                         float* deg, int* cnt) {
  int e = blockIdx.x * 256 + threadIdx.x;
  if (e < E_EDGES) {
    int c = ei[E_EDGES + e];
    atomicAdd(&deg[c], ew[e]);
    atomicAdd(&cnt[c], 1);
  }
}

__global__ void k_scan(const int* __restrict__ cnt, int* __restrict__ off,
                       int* __restrict__ cursor, const float* __restrict__ deg,
                       float* __restrict__ dinv) {
  __shared__ int s[1024];
  int t = threadIdx.x;
  int base = t * 16;
#pragma unroll
  for (int i = 0; i < 16; ++i) dinv[base + i] = rsqrtf(deg[base + i]);
  int loc[16]; int sum = 0;
#pragma unroll
  for (int i = 0; i < 16; ++i) { loc[i] = cnt[base + i]; sum += loc[i]; }
  s[t] = sum; __syncthreads();
  for (int d = 1; d < 1024; d <<= 1) {
    int v = (t >= d) ? s[t - d] : 0;
    __syncthreads();
    s[t] += v;
    __syncthreads();
  }
  int run = (t == 0) ? 0 : s[t - 1];
#pragma unroll
  for (int i = 0; i < 16; ++i) { off[base + i] = run; cursor[base + i] = run; run += loc[i]; }
  if (t == 1023) off[N_NODES] = run;
}

__global__ void k_scatter(const int* __restrict__ ei, const float* __restrict__ ew,
                          const float* __restrict__ dinv, int* cursor,
                          int* __restrict__ r2, float* __restrict__ w2) {
  int e = blockIdx.x * 256 + threadIdx.x;
  if (e < E_EDGES) {
    int r = ei[e], c = ei[E_EDGES + e];
    float w = dinv[r] * ew[e] * dinv[c];
    int p = atomicAdd(&cursor[c], 1);
    r2[p] = r; w2[p] = w;
  }
}

// ---------------- W1 pack (R5 verbatim: bf16, pad to 256, [k/8][n][8]) ----------------

__global__ void k_packW1(const float* __restrict__ W1, unsigned short* __restrict__ Wt,
                         float* deg, int* cnt) {
  int idx = blockIdx.x * 256 + threadIdx.x;   // < 16384*256
  if (idx < N_NODES) { deg[idx] = 1.0f; cnt[idx] = 0; }   // self-loop weight 1.0
  int n = idx & 255, k = idx >> 8;
  float v = (n < H1DIM) ? W1[(size_t)k * H1DIM + n] : 0.0f;
  Wt[(size_t)(k >> 3) * 2048 + n * 8 + (k & 7)] = f2bf(v);
}

// ---------------- GEMM1: h1p[ks] = x[:, kslice] @ W1pad  (bf16 MFMA) ----------------
// R10 verbatim (verified pass, 431.6 us) EXCEPT __launch_bounds__(512,2):
// (512,4) caps VGPR at 128/wave while live set ~140 -> likely K-loop spills.
// (512,2) lifts cap to 256; occupancy unchanged (2 blocks/CU by VGPR anyway).

#define LOADA(KT, AI)                                   \
  { const float* _p = xp0 + (KT) * BK;                  \
    aR[AI][0] = *(const fx4*)_p;                        \
    aR[AI][1] = *(const fx4*)(_p + 4); }

#define STAGEB(BUF, KT)                                                                  \
  { const unsigned short* _s = wbase + (size_t)(KT) * 8192 + (size_t)t * 8;              \
    char* _d = ldsB + (BUF) * 16384 + wv * 1024;                                         \
    __builtin_amdgcn_global_load_lds((const __attribute__((address_space(1))) void*)(_s),        (__attribute__((address_space(3))) void*)(_d),        16, 0, 0); \
    __builtin_amdgcn_global_load_lds((const __attribute__((address_space(1))) void*)(_s + 4096), (__attribute__((address_space(3))) void*)(_d + 8192), 16, 0, 0); }

#define WRITEA(AI)                                          \
  { ux4 _dv;                                                \
    _dv[0] = pk2(aR[AI][0][0], aR[AI][0][1]);               \
    _dv[1] = pk2(aR[AI][0][2], aR[AI][0][3]);               \
    _dv[2] = pk2(aR[AI][1][0], aR[AI][1][1]);               \
    _dv[3] = pk2(aR[AI][1][2], aR[AI][1][3]);               \
    *(ux4*)(ldsA + (AI) * 8192 + ((akblk * 128 + am) << 4)) = _dv; }

#define COMPUTE(BUF)                                                                     \
  { const char* _pa = ldsA + (BUF) * 8192;                                               \
    const char* _pb = ldsB + (BUF) * 16384;                                              \
    bf16x8 _af[4], _bf[4];                                                               \
    _Pragma("unroll")                                                                    \
    for (int mi = 0; mi < 4; ++mi)                                                       \
      _af[mi] = *(const bf16x8*)(_pa + ((g * 128 + wm * 64 + mi * 16 + l15) << 4));      \
    _Pragma("unroll")                                                                    \
    for (int ni = 0; ni < 4; ++ni)                                                       \
      _bf[ni] = *(const bf16x8*)(_pb + ((g * 256 + wn * 64 + ni * 16 + l15) << 4));      \
    _Pragma("unroll")                                                                    \
    for (int mi = 0; mi < 4; ++mi)                                                       \
      _Pragma("unroll")                                                                  \
      for (int ni = 0; ni < 4; ++ni)                                                     \
        acc[mi][ni] = __builtin_amdgcn_mfma_f32_16x16x32_bf16(_af[mi], _bf[ni], acc[mi][ni], 0, 0, 0); }

#define SYNC_VM(N)                                          \
  __builtin_amdgcn_sched_barrier(0);                        \
  asm volatile("s_waitcnt vmcnt(" #N ")" ::: "memory");     \
  asm volatile("s_waitcnt lgkmcnt(0)" ::: "memory");        \
  __builtin_amdgcn_s_barrier();                             \
  __builtin_amdgcn_sched_barrier(0);

#define GSTEP(KT, PAR)                 \
  STAGEB((PAR) ^ 1, (KT) + 1)          \
  __builtin_amdgcn_sched_barrier(0);   \
  LOADA((KT) + 2, PAR)                 \
  __builtin_amdgcn_sched_barrier(0);   \
  COMPUTE(PAR)                         \
  WRITEA((PAR) ^ 1)                    \
  SYNC_VM(2)

__launch_bounds__(512, 2)
__global__ void k_gemm1(const float* __restrict__ x, const unsigned short* __restrict__ Wt,
                        float* __restrict__ h1p) {
  __shared__ char lds[49152];       // A: [2][8192] @0, B: [2][16384] @16384
  const int t = threadIdx.x;
  const int wv = t >> 6;
  const int wm = wv >> 2, wn = wv & 3;
  const int ln = t & 63;
  const int g = ln >> 4, l15 = ln & 15;
  const int bid = blockIdx.x;
  const int ks = bid & 3;
  const size_t m0 = (size_t)(bid >> 2) * BM;
  const int k0 = ks * KLEN;

  // A staging coords: thread t -> (row = t/4 [0..127], kblk = t%4)
  const int am = t >> 2;
  const int akblk = t & 3;
  const float* xp0 = x + (m0 + am) * (size_t)KDIM + k0 + akblk * 8;
  const unsigned short* wbase = Wt + (size_t)k0 * 256;

  char* ldsA = lds;
  char* ldsB = lds + 16384;

  fx4 acc[4][4] = {};
  fx4 aR[2][2];

  // prologue: A(0),A(1) -> regs; B(0) staged; A(0) -> LDS; drain.
  LOADA(0, 0)
  LOADA(1, 1)
  STAGEB(0, 0)
  WRITEA(0)
  SYNC_VM(0)

  // steady: steps 0..125 (NT-2 = 126, unroll by 2 for literal parity)
  for (int kt = 0; kt < NT - 2; kt += 2) {
    GSTEP(kt + 0, 0)
    GSTEP(kt + 1, 1)
  }

  // step 126 (par 0): stage last B, no A load, drains.
  STAGEB(1, NT - 1)
  __builtin_amdgcn_sched_barrier(0);
  COMPUTE(0)
  WRITEA(1)
  SYNC_VM(0)
  // step 127 (par 1)
  COMPUTE(1)

  float* outp = h1p + (size_t)ks * ((size_t)N_NODES * BNP);
#pragma unroll
  for (int mi = 0; mi < 4; ++mi)
#pragma unroll
    for (int ni = 0; ni < 4; ++ni)
#pragma unroll
      for (int r = 0; r < 4; ++r)
        outp[(m0 + wm * 64 + mi * 16 + g * 4 + r) * BNP + wn * 64 + ni * 16 + l15] = acc[mi][ni][r];
}

// ---------------- reduce K-split partials -> compact bf16 h1 [16384][200] (R5 verbatim) ----------------

__global__ void k_reduce(const float* __restrict__ h1p, unsigned short* __restrict__ h1b) {
  size_t i = (size_t)blockIdx.x * 256 + threadIdx.x;   // < 1048576 fx4 units of padded grid
  int cb = (int)(i & 63);            // column block (4 cols each)
  if (cb < 50) {                     // cols 200..255 are zero padding: skip entirely
    const fx4* a = (const fx4*)h1p;
    fx4 v = a[i];
    v += a[i + 1048576]; v += a[i + 2097152]; v += a[i + 3145728];
    size_t row = i >> 6;
    ux2 o;
    o[0] = pk2(v[0], v[1]);
    o[1] = pk2(v[2], v[3]);
    *(ux2*)(h1b + row * H1DIM + cb * 4) = o;
  }
}

// ---------------- layer-1 aggregation + bias + relu (R5 verbatim) ----------------
// MEASUREMENT this round: launched TWICE (idempotent) -> t_agg1 by subtraction.

__global__ void k_agg1(const unsigned short* __restrict__ h1b, const int* __restrict__ r2,
                       const float* __restrict__ w2, const int* __restrict__ off,
                       const float* __restrict__ dinv, const float* __restrict__ b1,
                       float* __restrict__ h1r) {
  int c = blockIdx.x;
  int j = threadIdx.x;          // active: j < 200
  if (j >= H1DIM) return;
  int p0 = off[c], p1 = off[c + 1];
  float acc = 0.0f;
  int p = p0;
  for (; p + 4 <= p1; p += 4) {       // 4-way unroll: break the serial latency chain
    int ra = r2[p], rb = r2[p + 1], rc = r2[p + 2], rd = r2[p + 3];
    float wa = w2[p], wb = w2[p + 1], wc = w2[p + 2], wd = w2[p + 3];
    float va = bf2f((unsigned int)h1b[(size_t)ra * H1DIM + j]);
    float vb = bf2f((unsigned int)h1b[(size_t)rb * H1DIM + j]);
    float vc = bf2f((unsigned int)h1b[(size_t)rc * H1DIM + j]);
    float vd = bf2f((unsigned int)h1b[(size_t)rd * H1DIM + j]);
    acc += wa * va + wb * vb + wc * vc + wd * vd;
  }
  for (; p < p1; ++p)
    acc += w2[p] * bf2f((unsigned int)h1b[(size_t)r2[p] * H1DIM + j]);
  float d = dinv[c];
  acc += d * d * bf2f((unsigned int)h1b[(size_t)c * H1DIM + j]);
  acc += b1[j];
  h1r[(size_t)c * H1DIM + j] = fmaxf(acc, 0.0f);
}

// ---------------- layer-2 linear (R5 verbatim) ----------------

__global__ void k_gemm2(const float* __restrict__ h1r, const float* __restrict__ W2,
                        float* __restrict__ g) {
  __shared__ float w2s[H1DIM * H2DIM];
  int t = threadIdx.x;
  for (int i = t; i < H1DIM * H2DIM; i += 256) w2s[i] = W2[i];
  __syncthreads();
  int r = t >> 3, j = t & 7;
  size_t i = (size_t)blockIdx.x * 32 + r;
  const float* hrow = h1r + i * H1DIM;
  float acc = 0.0f;
#pragma unroll 8
  for (int k = 0; k < H1DIM; ++k) acc = fmaf(hrow[k], w2s[k * 8 + j], acc);
  g[i * 8 + j] = acc;
}

// ---------------- layer-2 aggregation + bias (R5 verbatim) ----------------

__global__ void k_agg2(const float* __restrict__ g, const int* __restrict__ r2,
                       const float* __restrict__ w2, const int* __restrict__ off,
                       const float* __restrict__ dinv, const float* __restrict__ b2,
                       float* __restrict__ out) {
  int t = threadIdx.x;
  int c = blockIdx.x * 32 + (t >> 3), j = t & 7;
  int p0 = off[c], p1 = off[c + 1];
  float acc = 0.0f;
  for (int p = p0; p < p1; ++p) acc += w2[p] * g[(size_t)r2[p] * 8 + j];
  float d = dinv[c];
  out[(size_t)c * 8 + j] = acc + d * d * g[(size_t)c * 8 + j] + b2[j];
}

// ---------------- launch ----------------

extern "C" void kernel_launch(void* const* d_in, const int* in_sizes, int n_in,
                              void* d_out, int out_size, void* d_ws, size_t ws_size,
                              hipStream_t stream) {
  (void)in_sizes; (void)n_in; (void)out_size; (void)ws_size;
  const float* x  = (const float*)d_in[0];
  const int*   ei = (const int*)d_in[1];
  const float* ew = (const float*)d_in[2];
  const float* W1 = (const float*)d_in[3];
  const float* b1 = (const float*)d_in[4];
  const float* W2 = (const float*)d_in[5];
  const float* b2 = (const float*)d_in[6];
  float* out = (float*)d_out;
  char* ws = (char*)d_ws;

  float* deg    = (float*)(ws + 0);          // 64 KiB
  float* dinv   = (float*)(ws + 65536);      // 64 KiB
  int*   cnt    = (int*)  (ws + 131072);     // 64 KiB
  int*   off    = (int*)  (ws + 196608);     // 16385 ints
  int*   cursor = (int*)  (ws + 262400);     // 64 KiB
  int*   r2     = (int*)  (ws + 327936);     // 2 MiB
  float* w2     = (float*)(ws + 2425088);    // 2 MiB
  unsigned short* Wt = (unsigned short*)(ws + 4522240);   // 8 MiB bf16 packed
  float* h1p    = (float*)(ws + 12910848);   // 4 * [16384][256] f32 = 64 MiB
  float* h1r    = (float*)(ws + 80019712);   // [16384][200] f32
  float* g      = (float*)(ws + 93126912);   // [16384][8] f32
  unsigned short* h1b = (unsigned short*)(ws + 93651200); // [16384][200] bf16 = 6.55 MiB

  k_packW1 <<<16384, 256, 0, stream>>>(W1, Wt, deg, cnt);
  k_degcnt <<<2048,  256, 0, stream>>>(ei, ew, deg, cnt);
  k_scan   <<<1,    1024, 0, stream>>>(cnt, off, cursor, deg, dinv);
  k_scatter<<<2048,  256, 0, stream>>>(ei, ew, dinv, cursor, r2, w2);
  k_gemm1  <<<512,   512, 0, stream>>>(x, Wt, h1p);
  k_reduce <<<4096,  256, 0, stream>>>(h1p, h1b);
  // MEASUREMENT: agg1 launched twice (idempotent). t_agg1 = dur - (431.6 - spill_gain).
  k_agg1   <<<16384, 256, 0, stream>>>(h1b, r2, w2, off, dinv, b1, h1r);
  k_agg1   <<<16384, 256, 0, stream>>>(h1b, r2, w2, off, dinv, b1, h1r);
  k_gemm2  <<<512,   256, 0, stream>>>(h1r, W2, g);
  k_agg2   <<<512,   256, 0, stream>>>(g, r2, w2, off, dinv, b2, out);
}

// Round 13
// 420.169 us; speedup vs baseline: 1.1330x; 1.1330x over previous
//
#include <hip/hip_runtime.h>

#define N_NODES 16384
#define KDIM    16384
#define E_EDGES 524288
#define H1DIM   200
#define H2DIM   8
#define BNP     256     // padded H1

#define BM 128
#define BK 32
#define KSPLIT 4
#define KLEN 4096       // KDIM / KSPLIT
#define NT 128          // KLEN / BK

typedef __attribute__((ext_vector_type(8))) short bf16x8;
typedef __attribute__((ext_vector_type(4))) float fx4;
typedef __attribute__((ext_vector_type(4))) unsigned int ux4;
typedef __attribute__((ext_vector_type(2))) unsigned int ux2;

__device__ __forceinline__ unsigned short f2bf(float f) {
  unsigned int u = __builtin_bit_cast(unsigned int, f);
  return (unsigned short)((u + 0x7FFFu + ((u >> 16) & 1u)) >> 16);  // RNE
}
__device__ __forceinline__ unsigned int pk2(float a, float b) {
  return (unsigned int)f2bf(a) | ((unsigned int)f2bf(b) << 16);
}
__device__ __forceinline__ float bf2f(unsigned int u) {
  return __builtin_bit_cast(float, u << 16);
}

// ---------------- degree / CSR build (R5 verbatim) ----------------

__global__ void k_degcnt(const int* __restrict__ ei, const float* __restrict__ ew,
                         float* deg, int* cnt) {
  int e = blockIdx.x * 256 + threadIdx.x;
  if (e < E_EDGES) {
    int c = ei[E_EDGES + e];
    atomicAdd(&deg[c], ew[e]);
    atomicAdd(&cnt[c], 1);
  }
}

__global__ void k_scan(const int* __restrict__ cnt, int* __restrict__ off,
                       int* __restrict__ cursor, const float* __restrict__ deg,
                       float* __restrict__ dinv) {
  __shared__ int s[1024];
  int t = threadIdx.x;
  int base = t * 16;
#pragma unroll
  for (int i = 0; i < 16; ++i) dinv[base + i] = rsqrtf(deg[base + i]);
  int loc[16]; int sum = 0;
#pragma unroll
  for (int i = 0; i < 16; ++i) { loc[i] = cnt[base + i]; sum += loc[i]; }
  s[t] = sum; __syncthreads();
  for (int d = 1; d < 1024; d <<= 1) {
    int v = (t >= d) ? s[t - d] : 0;
    __syncthreads();
    s[t] += v;
    __syncthreads();
  }
  int run = (t == 0) ? 0 : s[t - 1];
#pragma unroll
  for (int i = 0; i < 16; ++i) { off[base + i] = run; cursor[base + i] = run; run += loc[i]; }
  if (t == 1023) off[N_NODES] = run;
}

__global__ void k_scatter(const int* __restrict__ ei, const float* __restrict__ ew,
                          const float* __restrict__ dinv, int* cursor,
                          int* __restrict__ r2, float* __restrict__ w2) {
  int e = blockIdx.x * 256 + threadIdx.x;
  if (e < E_EDGES) {
    int r = ei[e], c = ei[E_EDGES + e];
    float w = dinv[r] * ew[e] * dinv[c];
    int p = atomicAdd(&cursor[c], 1);
    r2[p] = r; w2[p] = w;
  }
}

// ---------------- W1 pack: COALESCED (bisect: this is the ONLY change vs R10). ----------------
// thread = (k-octet k8, col n): reads W1[(k8*8+i)*200+n] (consecutive n across lanes =
// coalesced), writes 16 B contiguous per thread to Wt[k8*2048 + n*8 + i]. Identical
// layout to the R5 pack. Fuses deg/cnt init (idx < 16384 covered by k8 < 64).

__global__ void k_packW1(const float* __restrict__ W1, unsigned short* __restrict__ Wt,
                         float* deg, int* cnt) {
  int n = threadIdx.x;            // 0..255
  int k8 = blockIdx.x;            // 0..2047
  int idx = k8 * 256 + n;
  if (idx < N_NODES) { deg[idx] = 1.0f; cnt[idx] = 0; }   // self-loop weight 1.0
  unsigned short v[8];
  if (n < H1DIM) {
    const float* base = W1 + (size_t)(k8 * 8) * H1DIM + n;
#pragma unroll
    for (int i = 0; i < 8; ++i) v[i] = f2bf(base[(size_t)i * H1DIM]);
  } else {
#pragma unroll
    for (int i = 0; i < 8; ++i) v[i] = 0;
  }
  ux4 o;
  o[0] = (unsigned int)v[0] | ((unsigned int)v[1] << 16);
  o[1] = (unsigned int)v[2] | ((unsigned int)v[3] << 16);
  o[2] = (unsigned int)v[4] | ((unsigned int)v[5] << 16);
  o[3] = (unsigned int)v[6] | ((unsigned int)v[7] << 16);
  *(ux4*)(Wt + (size_t)k8 * 2048 + n * 8) = o;
}

// ---------------- GEMM1: h1p[ks] = x[:, kslice] @ W1pad  (bf16 MFMA) ----------------
// R10 VERBATIM (verified pass, 431.6 us): BM=128, 512 threads (8 waves 2x4), 512
// blocks, ks=bid&3 XCD-pure, counted-vmcnt schedule, __launch_bounds__(512,4).

#define LOADA(KT, AI)                                   \
  { const float* _p = xp0 + (KT) * BK;                  \
    aR[AI][0] = *(const fx4*)_p;                        \
    aR[AI][1] = *(const fx4*)(_p + 4); }

#define STAGEB(BUF, KT)                                                                  \
  { const unsigned short* _s = wbase + (size_t)(KT) * 8192 + (size_t)t * 8;              \
    char* _d = ldsB + (BUF) * 16384 + wv * 1024;                                         \
    __builtin_amdgcn_global_load_lds((const __attribute__((address_space(1))) void*)(_s),        (__attribute__((address_space(3))) void*)(_d),        16, 0, 0); \
    __builtin_amdgcn_global_load_lds((const __attribute__((address_space(1))) void*)(_s + 4096), (__attribute__((address_space(3))) void*)(_d + 8192), 16, 0, 0); }

#define WRITEA(AI)                                          \
  { ux4 _dv;                                                \
    _dv[0] = pk2(aR[AI][0][0], aR[AI][0][1]);               \
    _dv[1] = pk2(aR[AI][0][2], aR[AI][0][3]);               \
    _dv[2] = pk2(aR[AI][1][0], aR[AI][1][1]);               \
    _dv[3] = pk2(aR[AI][1][2], aR[AI][1][3]);               \
    *(ux4*)(ldsA + (AI) * 8192 + ((akblk * 128 + am) << 4)) = _dv; }

#define COMPUTE(BUF)                                                                     \
  { const char* _pa = ldsA + (BUF) * 8192;                                               \
    const char* _pb = ldsB + (BUF) * 16384;                                              \
    bf16x8 _af[4], _bf[4];                                                               \
    _Pragma("unroll")                                                                    \
    for (int mi = 0; mi < 4; ++mi)                                                       \
      _af[mi] = *(const bf16x8*)(_pa + ((g * 128 + wm * 64 + mi * 16 + l15) << 4));      \
    _Pragma("unroll")                                                                    \
    for (int ni = 0; ni < 4; ++ni)                                                       \
      _bf[ni] = *(const bf16x8*)(_pb + ((g * 256 + wn * 64 + ni * 16 + l15) << 4));      \
    _Pragma("unroll")                                                                    \
    for (int mi = 0; mi < 4; ++mi)                                                       \
      _Pragma("unroll")                                                                  \
      for (int ni = 0; ni < 4; ++ni)                                                     \
        acc[mi][ni] = __builtin_amdgcn_mfma_f32_16x16x32_bf16(_af[mi], _bf[ni], acc[mi][ni], 0, 0, 0); }

#define SYNC_VM(N)                                          \
  __builtin_amdgcn_sched_barrier(0);                        \
  asm volatile("s_waitcnt vmcnt(" #N ")" ::: "memory");     \
  asm volatile("s_waitcnt lgkmcnt(0)" ::: "memory");        \
  __builtin_amdgcn_s_barrier();                             \
  __builtin_amdgcn_sched_barrier(0);

#define GSTEP(KT, PAR)                 \
  STAGEB((PAR) ^ 1, (KT) + 1)          \
  __builtin_amdgcn_sched_barrier(0);   \
  LOADA((KT) + 2, PAR)                 \
  __builtin_amdgcn_sched_barrier(0);   \
  COMPUTE(PAR)                         \
  WRITEA((PAR) ^ 1)                    \
  SYNC_VM(2)

__launch_bounds__(512, 4)
__global__ void k_gemm1(const float* __restrict__ x, const unsigned short* __restrict__ Wt,
                        float* __restrict__ h1p) {
  __shared__ char lds[49152];       // A: [2][8192] @0, B: [2][16384] @16384
  const int t = threadIdx.x;
  const int wv = t >> 6;
  const int wm = wv >> 2, wn = wv & 3;
  const int ln = t & 63;
  const int g = ln >> 4, l15 = ln & 15;
  const int bid = blockIdx.x;
  const int ks = bid & 3;
  const size_t m0 = (size_t)(bid >> 2) * BM;
  const int k0 = ks * KLEN;

  // A staging coords: thread t -> (row = t/4 [0..127], kblk = t%4)
  const int am = t >> 2;
  const int akblk = t & 3;
  const float* xp0 = x + (m0 + am) * (size_t)KDIM + k0 + akblk * 8;
  const unsigned short* wbase = Wt + (size_t)k0 * 256;

  char* ldsA = lds;
  char* ldsB = lds + 16384;

  fx4 acc[4][4] = {};
  fx4 aR[2][2];

  // prologue: A(0),A(1) -> regs; B(0) staged; A(0) -> LDS; drain.
  LOADA(0, 0)
  LOADA(1, 1)
  STAGEB(0, 0)
  WRITEA(0)
  SYNC_VM(0)

  // steady: steps 0..125 (NT-2 = 126, unroll by 2 for literal parity)
  for (int kt = 0; kt < NT - 2; kt += 2) {
    GSTEP(kt + 0, 0)
    GSTEP(kt + 1, 1)
  }

  // step 126 (par 0): stage last B, no A load, drains.
  STAGEB(1, NT - 1)
  __builtin_amdgcn_sched_barrier(0);
  COMPUTE(0)
  WRITEA(1)
  SYNC_VM(0)
  // step 127 (par 1)
  COMPUTE(1)

  float* outp = h1p + (size_t)ks * ((size_t)N_NODES * BNP);
#pragma unroll
  for (int mi = 0; mi < 4; ++mi)
#pragma unroll
    for (int ni = 0; ni < 4; ++ni)
#pragma unroll
      for (int r = 0; r < 4; ++r)
        outp[(m0 + wm * 64 + mi * 16 + g * 4 + r) * BNP + wn * 64 + ni * 16 + l15] = acc[mi][ni][r];
}

// ---------------- reduce K-split partials -> compact bf16 h1 [16384][200] (R5 verbatim) ----------------

__global__ void k_reduce(const float* __restrict__ h1p, unsigned short* __restrict__ h1b) {
  size_t i = (size_t)blockIdx.x * 256 + threadIdx.x;   // < 1048576 fx4 units of padded grid
  int cb = (int)(i & 63);            // column block (4 cols each)
  if (cb < 50) {                     // cols 200..255 are zero padding: skip entirely
    const fx4* a = (const fx4*)h1p;
    fx4 v = a[i];
    v += a[i + 1048576]; v += a[i + 2097152]; v += a[i + 3145728];
    size_t row = i >> 6;
    ux2 o;
    o[0] = pk2(v[0], v[1]);
    o[1] = pk2(v[2], v[3]);
    *(ux2*)(h1b + row * H1DIM + cb * 4) = o;
  }
}

// ---------------- layer-1 aggregation + bias + relu (R5 verbatim) ----------------

__global__ void k_agg1(const unsigned short* __restrict__ h1b, const int* __restrict__ r2,
                       const float* __restrict__ w2, const int* __restrict__ off,
                       const float* __restrict__ dinv, const float* __restrict__ b1,
                       float* __restrict__ h1r) {
  int c = blockIdx.x;
  int j = threadIdx.x;          // active: j < 200
  if (j >= H1DIM) return;
  int p0 = off[c], p1 = off[c + 1];
  float acc = 0.0f;
  int p = p0;
  for (; p + 4 <= p1; p += 4) {       // 4-way unroll: break the serial latency chain
    int ra = r2[p], rb = r2[p + 1], rc = r2[p + 2], rd = r2[p + 3];
    float wa = w2[p], wb = w2[p + 1], wc = w2[p + 2], wd = w2[p + 3];
    float va = bf2f((unsigned int)h1b[(size_t)ra * H1DIM + j]);
    float vb = bf2f((unsigned int)h1b[(size_t)rb * H1DIM + j]);
    float vc = bf2f((unsigned int)h1b[(size_t)rc * H1DIM + j]);
    float vd = bf2f((unsigned int)h1b[(size_t)rd * H1DIM + j]);
    acc += wa * va + wb * vb + wc * vc + wd * vd;
  }
  for (; p < p1; ++p)
    acc += w2[p] * bf2f((unsigned int)h1b[(size_t)r2[p] * H1DIM + j]);
  float d = dinv[c];
  acc += d * d * bf2f((unsigned int)h1b[(size_t)c * H1DIM + j]);
  acc += b1[j];
  h1r[(size_t)c * H1DIM + j] = fmaxf(acc, 0.0f);
}

// ---------------- layer-2 linear (R5 verbatim) ----------------

__global__ void k_gemm2(const float* __restrict__ h1r, const float* __restrict__ W2,
                        float* __restrict__ g) {
  __shared__ float w2s[H1DIM * H2DIM];
  int t = threadIdx.x;
  for (int i = t; i < H1DIM * H2DIM; i += 256) w2s[i] = W2[i];
  __syncthreads();
  int r = t >> 3, j = t & 7;
  size_t i = (size_t)blockIdx.x * 32 + r;
  const float* hrow = h1r + i * H1DIM;
  float acc = 0.0f;
#pragma unroll 8
  for (int k = 0; k < H1DIM; ++k) acc = fmaf(hrow[k], w2s[k * 8 + j], acc);
  g[i * 8 + j] = acc;
}

// ---------------- layer-2 aggregation + bias (R5 verbatim) ----------------

__global__ void k_agg2(const float* __restrict__ g, const int* __restrict__ r2,
                       const float* __restrict__ w2, const int* __restrict__ off,
                       const float* __restrict__ dinv, const float* __restrict__ b2,
                       float* __restrict__ out) {
  int t = threadIdx.x;
  int c = blockIdx.x * 32 + (t >> 3), j = t & 7;
  int p0 = off[c], p1 = off[c + 1];
  float acc = 0.0f;
  for (int p = p0; p < p1; ++p) acc += w2[p] * g[(size_t)r2[p] * 8 + j];
  float d = dinv[c];
  out[(size_t)c * 8 + j] = acc + d * d * g[(size_t)c * 8 + j] + b2[j];
}

// ---------------- launch ----------------

extern "C" void kernel_launch(void* const* d_in, const int* in_sizes, int n_in,
                              void* d_out, int out_size, void* d_ws, size_t ws_size,
                              hipStream_t stream) {
  (void)in_sizes; (void)n_in; (void)out_size; (void)ws_size;
  const float* x  = (const float*)d_in[0];
  const int*   ei = (const int*)d_in[1];
  const float* ew = (const float*)d_in[2];
  const float* W1 = (const float*)d_in[3];
  const float* b1 = (const float*)d_in[4];
  const float* W2 = (const float*)d_in[5];
  const float* b2 = (const float*)d_in[6];
  float* out = (float*)d_out;
  char* ws = (char*)d_ws;

  float* deg    = (float*)(ws + 0);          // 64 KiB
  float* dinv   = (float*)(ws + 65536);      // 64 KiB
  int*   cnt    = (int*)  (ws + 131072);     // 64 KiB
  int*   off    = (int*)  (ws + 196608);     // 16385 ints
  int*   cursor = (int*)  (ws + 262400);     // 64 KiB
  int*   r2     = (int*)  (ws + 327936);     // 2 MiB
  float* w2     = (float*)(ws + 2425088);    // 2 MiB
  unsigned short* Wt = (unsigned short*)(ws + 4522240);   // 8 MiB bf16 packed
  float* h1p    = (float*)(ws + 12910848);   // 4 * [16384][256] f32 = 64 MiB
  float* h1r    = (float*)(ws + 80019712);   // [16384][200] f32
  float* g      = (float*)(ws + 93126912);   // [16384][8] f32
  unsigned short* h1b = (unsigned short*)(ws + 93651200); // [16384][200] bf16 = 6.55 MiB

  k_packW1 <<<2048,  256, 0, stream>>>(W1, Wt, deg, cnt);
  k_degcnt <<<2048,  256, 0, stream>>>(ei, ew, deg, cnt);
  k_scan   <<<1,    1024, 0, stream>>>(cnt, off, cursor, deg, dinv);
  k_scatter<<<2048,  256, 0, stream>>>(ei, ew, dinv, cursor, r2, w2);
  k_gemm1  <<<512,   512, 0, stream>>>(x, Wt, h1p);
  k_reduce <<<4096,  256, 0, stream>>>(h1p, h1b);
  k_agg1   <<<16384, 256, 0, stream>>>(h1b, r2, w2, off, dinv, b1, h1r);
  k_gemm2  <<<512,   256, 0, stream>>>(h1r, W2, g);
  k_agg2   <<<512,   256, 0, stream>>>(g, r2, w2, off, dinv, b2, out);
}

// Round 14
// 419.467 us; speedup vs baseline: 1.1349x; 1.0017x over previous
//
#include <hip/hip_runtime.h>

#define N_NODES 16384
#define KDIM    16384
#define E_EDGES 524288
#define H1DIM   200
#define H2DIM   8
#define BNP     256     // padded H1

#define BM 128
#define BK 32
#define KSPLIT 4
#define KLEN 4096       // KDIM / KSPLIT
#define NT 128          // KLEN / BK

typedef __attribute__((ext_vector_type(8))) short bf16x8;
typedef __attribute__((ext_vector_type(4))) float fx4;
typedef __attribute__((ext_vector_type(4))) unsigned int ux4;
typedef __attribute__((ext_vector_type(2))) unsigned int ux2;

__device__ __forceinline__ unsigned short f2bf(float f) {
  unsigned int u = __builtin_bit_cast(unsigned int, f);
  return (unsigned short)((u + 0x7FFFu + ((u >> 16) & 1u)) >> 16);  // RNE
}
__device__ __forceinline__ unsigned int pk2(float a, float b) {
  return (unsigned int)f2bf(a) | ((unsigned int)f2bf(b) << 16);
}
__device__ __forceinline__ float bf2f(unsigned int u) {
  return __builtin_bit_cast(float, u << 16);
}

// ---------------- degree / CSR build (R5 verbatim) ----------------

__global__ void k_degcnt(const int* __restrict__ ei, const float* __restrict__ ew,
                         float* deg, int* cnt) {
  int e = blockIdx.x * 256 + threadIdx.x;
  if (e < E_EDGES) {
    int c = ei[E_EDGES + e];
    atomicAdd(&deg[c], ew[e]);
    atomicAdd(&cnt[c], 1);
  }
}

__global__ void k_scan(const int* __restrict__ cnt, int* __restrict__ off,
                       int* __restrict__ cursor, const float* __restrict__ deg,
                       float* __restrict__ dinv) {
  __shared__ int s[1024];
  int t = threadIdx.x;
  int base = t * 16;
#pragma unroll
  for (int i = 0; i < 16; ++i) dinv[base + i] = rsqrtf(deg[base + i]);
  int loc[16]; int sum = 0;
#pragma unroll
  for (int i = 0; i < 16; ++i) { loc[i] = cnt[base + i]; sum += loc[i]; }
  s[t] = sum; __syncthreads();
  for (int d = 1; d < 1024; d <<= 1) {
    int v = (t >= d) ? s[t - d] : 0;
    __syncthreads();
    s[t] += v;
    __syncthreads();
  }
  int run = (t == 0) ? 0 : s[t - 1];
#pragma unroll
  for (int i = 0; i < 16; ++i) { off[base + i] = run; cursor[base + i] = run; run += loc[i]; }
  if (t == 1023) off[N_NODES] = run;
}

__global__ void k_scatter(const int* __restrict__ ei, const float* __restrict__ ew,
                          const float* __restrict__ dinv, int* cursor,
                          int* __restrict__ r2, float* __restrict__ w2) {
  int e = blockIdx.x * 256 + threadIdx.x;
  if (e < E_EDGES) {
    int r = ei[e], c = ei[E_EDGES + e];
    float w = dinv[r] * ew[e] * dinv[c];
    int p = atomicAdd(&cursor[c], 1);
    r2[p] = r; w2[p] = w;
  }
}

// ---------------- W1 pack: COALESCED (R13 verbatim, verified) ----------------

__global__ void k_packW1(const float* __restrict__ W1, unsigned short* __restrict__ Wt,
                         float* deg, int* cnt) {
  int n = threadIdx.x;            // 0..255
  int k8 = blockIdx.x;            // 0..2047
  int idx = k8 * 256 + n;
  if (idx < N_NODES) { deg[idx] = 1.0f; cnt[idx] = 0; }   // self-loop weight 1.0
  unsigned short v[8];
  if (n < H1DIM) {
    const float* base = W1 + (size_t)(k8 * 8) * H1DIM + n;
#pragma unroll
    for (int i = 0; i < 8; ++i) v[i] = f2bf(base[(size_t)i * H1DIM]);
  } else {
#pragma unroll
    for (int i = 0; i < 8; ++i) v[i] = 0;
  }
  ux4 o;
  o[0] = (unsigned int)v[0] | ((unsigned int)v[1] << 16);
  o[1] = (unsigned int)v[2] | ((unsigned int)v[3] << 16);
  o[2] = (unsigned int)v[4] | ((unsigned int)v[5] << 16);
  o[3] = (unsigned int)v[6] | ((unsigned int)v[7] << 16);
  *(ux4*)(Wt + (size_t)k8 * 2048 + n * 8) = o;
}

// ---------------- GEMM1 (R10/R13 verbatim, verified 431.6 -> 420.2 baseline) ----------------

#define LOADA(KT, AI)                                   \
  { const float* _p = xp0 + (KT) * BK;                  \
    aR[AI][0] = *(const fx4*)_p;                        \
    aR[AI][1] = *(const fx4*)(_p + 4); }

#define STAGEB(BUF, KT)                                                                  \
  { const unsigned short* _s = wbase + (size_t)(KT) * 8192 + (size_t)t * 8;              \
    char* _d = ldsB + (BUF) * 16384 + wv * 1024;                                         \
    __builtin_amdgcn_global_load_lds((const __attribute__((address_space(1))) void*)(_s),        (__attribute__((address_space(3))) void*)(_d),        16, 0, 0); \
    __builtin_amdgcn_global_load_lds((const __attribute__((address_space(1))) void*)(_s + 4096), (__attribute__((address_space(3))) void*)(_d + 8192), 16, 0, 0); }

#define WRITEA(AI)                                          \
  { ux4 _dv;                                                \
    _dv[0] = pk2(aR[AI][0][0], aR[AI][0][1]);               \
    _dv[1] = pk2(aR[AI][0][2], aR[AI][0][3]);               \
    _dv[2] = pk2(aR[AI][1][0], aR[AI][1][1]);               \
    _dv[3] = pk2(aR[AI][1][2], aR[AI][1][3]);               \
    *(ux4*)(ldsA + (AI) * 8192 + ((akblk * 128 + am) << 4)) = _dv; }

#define COMPUTE(BUF)                                                                     \
  { const char* _pa = ldsA + (BUF) * 8192;                                               \
    const char* _pb = ldsB + (BUF) * 16384;                                              \
    bf16x8 _af[4], _bf[4];                                                               \
    _Pragma("unroll")                                                                    \
    for (int mi = 0; mi < 4; ++mi)                                                       \
      _af[mi] = *(const bf16x8*)(_pa + ((g * 128 + wm * 64 + mi * 16 + l15) << 4));      \
    _Pragma("unroll")                                                                    \
    for (int ni = 0; ni < 4; ++ni)                                                       \
      _bf[ni] = *(const bf16x8*)(_pb + ((g * 256 + wn * 64 + ni * 16 + l15) << 4));      \
    _Pragma("unroll")                                                                    \
    for (int mi = 0; mi < 4; ++mi)                                                       \
      _Pragma("unroll")                                                                  \
      for (int ni = 0; ni < 4; ++ni)                                                     \
        acc[mi][ni] = __builtin_amdgcn_mfma_f32_16x16x32_bf16(_af[mi], _bf[ni], acc[mi][ni], 0, 0, 0); }

#define SYNC_VM(N)                                          \
  __builtin_amdgcn_sched_barrier(0);                        \
  asm volatile("s_waitcnt vmcnt(" #N ")" ::: "memory");     \
  asm volatile("s_waitcnt lgkmcnt(0)" ::: "memory");        \
  __builtin_amdgcn_s_barrier();                             \
  __builtin_amdgcn_sched_barrier(0);

#define GSTEP(KT, PAR)                 \
  STAGEB((PAR) ^ 1, (KT) + 1)          \
  __builtin_amdgcn_sched_barrier(0);   \
  LOADA((KT) + 2, PAR)                 \
  __builtin_amdgcn_sched_barrier(0);   \
  COMPUTE(PAR)                         \
  WRITEA((PAR) ^ 1)                    \
  SYNC_VM(2)

__launch_bounds__(512, 4)
__global__ void k_gemm1(const float* __restrict__ x, const unsigned short* __restrict__ Wt,
                        float* __restrict__ h1p) {
  __shared__ char lds[49152];       // A: [2][8192] @0, B: [2][16384] @16384
  const int t = threadIdx.x;
  const int wv = t >> 6;
  const int wm = wv >> 2, wn = wv & 3;
  const int ln = t & 63;
  const int g = ln >> 4, l15 = ln & 15;
  const int bid = blockIdx.x;
  const int ks = bid & 3;
  const size_t m0 = (size_t)(bid >> 2) * BM;
  const int k0 = ks * KLEN;

  const int am = t >> 2;
  const int akblk = t & 3;
  const float* xp0 = x + (m0 + am) * (size_t)KDIM + k0 + akblk * 8;
  const unsigned short* wbase = Wt + (size_t)k0 * 256;

  char* ldsA = lds;
  char* ldsB = lds + 16384;

  fx4 acc[4][4] = {};
  fx4 aR[2][2];

  LOADA(0, 0)
  LOADA(1, 1)
  STAGEB(0, 0)
  WRITEA(0)
  SYNC_VM(0)

  for (int kt = 0; kt < NT - 2; kt += 2) {
    GSTEP(kt + 0, 0)
    GSTEP(kt + 1, 1)
  }

  STAGEB(1, NT - 1)
  __builtin_amdgcn_sched_barrier(0);
  COMPUTE(0)
  WRITEA(1)
  SYNC_VM(0)
  COMPUTE(1)

  float* outp = h1p + (size_t)ks * ((size_t)N_NODES * BNP);
#pragma unroll
  for (int mi = 0; mi < 4; ++mi)
#pragma unroll
    for (int ni = 0; ni < 4; ++ni)
#pragma unroll
      for (int r = 0; r < 4; ++r)
        outp[(m0 + wm * 64 + mi * 16 + g * 4 + r) * BNP + wn * 64 + ni * 16 + l15] = acc[mi][ni][r];
}

// ---------------- reduce: full-occupancy grid (819200 items = 3200 blocks exactly) ----------------

__global__ void k_reduce(const float* __restrict__ h1p, unsigned short* __restrict__ h1b) {
  int i = blockIdx.x * 256 + threadIdx.x;   // < 819200 = 16384 rows * 50 col-blocks
  int row = i / 50, cb = i % 50;
  const fx4* a = (const fx4*)h1p;
  size_t idx = (size_t)row * 64 + cb;
  fx4 v = a[idx];
  v += a[idx + 1048576]; v += a[idx + 2097152]; v += a[idx + 3145728];
  ux2 o;
  o[0] = pk2(v[0], v[1]);
  o[1] = pk2(v[2], v[3]);
  *(ux2*)(h1b + (size_t)row * H1DIM + cb * 4) = o;
}

// ---------------- layer-1 aggregation + bias + relu + layer-2 linear (FUSED, R4-proven) ----------------

__global__ void k_agg1(const unsigned short* __restrict__ h1b, const int* __restrict__ r2,
                       const float* __restrict__ w2, const int* __restrict__ off,
                       const float* __restrict__ dinv, const float* __restrict__ b1,
                       const float* __restrict__ W2, float* __restrict__ g) {
  __shared__ float sh[H1DIM];
  __shared__ float w2s[H1DIM * H2DIM];
  __shared__ float red[256];
  int c = blockIdx.x;
  int t = threadIdx.x;
  if (t < H1DIM) {
    int p0 = off[c], p1 = off[c + 1];
    float acc = 0.0f;
    int p = p0;
    for (; p + 4 <= p1; p += 4) {       // 4-way unroll: break the serial latency chain
      int ra = r2[p], rb = r2[p + 1], rc = r2[p + 2], rd = r2[p + 3];
      float wa = w2[p], wb = w2[p + 1], wc = w2[p + 2], wd = w2[p + 3];
      float va = bf2f((unsigned int)h1b[(size_t)ra * H1DIM + t]);
      float vb = bf2f((unsigned int)h1b[(size_t)rb * H1DIM + t]);
      float vc = bf2f((unsigned int)h1b[(size_t)rc * H1DIM + t]);
      float vd = bf2f((unsigned int)h1b[(size_t)rd * H1DIM + t]);
      acc += wa * va + wb * vb + wc * vc + wd * vd;
    }
    for (; p < p1; ++p)
      acc += w2[p] * bf2f((unsigned int)h1b[(size_t)r2[p] * H1DIM + t]);
    float d = dinv[c];
    acc += d * d * bf2f((unsigned int)h1b[(size_t)c * H1DIM + t]);
    sh[t] = fmaxf(acc + b1[t], 0.0f);
  } else {
    // idle threads prefetch W2 into LDS during the gather
    for (int i = t - H1DIM; i < H1DIM * H2DIM; i += 256 - H1DIM) w2s[i] = W2[i];
  }
  __syncthreads();
  // layer-2 linear for this row: g[c][jo] = sum_k relu_row[k] * W2[k][jo]
  int jo = t & 7, kc = t >> 3;
  float part = 0.0f;
  for (int k = kc; k < H1DIM; k += 32) part += sh[k] * w2s[k * 8 + jo];
  red[t] = part;
  __syncthreads();
#pragma unroll
  for (int s = 16; s >= 1; s >>= 1) {
    if (kc < s) red[t] += red[t + s * 8];
    __syncthreads();
  }
  if (t < 8) g[(size_t)c * 8 + t] = red[t];
}

// ---------------- layer-2 aggregation + bias (R5 verbatim) ----------------

__global__ void k_agg2(const float* __restrict__ g, const int* __restrict__ r2,
                       const float* __restrict__ w2, const int* __restrict__ off,
                       const float* __restrict__ dinv, const float* __restrict__ b2,
                       float* __restrict__ out) {
  int t = threadIdx.x;
  int c = blockIdx.x * 32 + (t >> 3), j = t & 7;
  int p0 = off[c], p1 = off[c + 1];
  float acc = 0.0f;
  for (int p = p0; p < p1; ++p) acc += w2[p] * g[(size_t)r2[p] * 8 + j];
  float d = dinv[c];
  out[(size_t)c * 8 + j] = acc + d * d * g[(size_t)c * 8 + j] + b2[j];
}

// ---------------- launch ----------------

extern "C" void kernel_launch(void* const* d_in, const int* in_sizes, int n_in,
                              void* d_out, int out_size, void* d_ws, size_t ws_size,
                              hipStream_t stream) {
  (void)in_sizes; (void)n_in; (void)out_size; (void)ws_size;
  const float* x  = (const float*)d_in[0];
  const int*   ei = (const int*)d_in[1];
  const float* ew = (const float*)d_in[2];
  const float* W1 = (const float*)d_in[3];
  const float* b1 = (const float*)d_in[4];
  const float* W2 = (const float*)d_in[5];
  const float* b2 = (const float*)d_in[6];
  float* out = (float*)d_out;
  char* ws = (char*)d_ws;

  float* deg    = (float*)(ws + 0);          // 64 KiB
  float* dinv   = (float*)(ws + 65536);      // 64 KiB
  int*   cnt    = (int*)  (ws + 131072);     // 64 KiB
  int*   off    = (int*)  (ws + 196608);     // 16385 ints
  int*   cursor = (int*)  (ws + 262400);     // 64 KiB
  int*   r2     = (int*)  (ws + 327936);     // 2 MiB
  float* w2     = (float*)(ws + 2425088);    // 2 MiB
  unsigned short* Wt = (unsigned short*)(ws + 4522240);   // 8 MiB bf16 packed
  float* h1p    = (float*)(ws + 12910848);   // 4 * [16384][256] f32 = 64 MiB
  float* g      = (float*)(ws + 93126912);   // [16384][8] f32
  unsigned short* h1b = (unsigned short*)(ws + 93651200); // [16384][200] bf16 = 6.55 MiB

  k_packW1 <<<2048,  256, 0, stream>>>(W1, Wt, deg, cnt);
  k_degcnt <<<2048,  256, 0, stream>>>(ei, ew, deg, cnt);
  k_scan   <<<1,    1024, 0, stream>>>(cnt, off, cursor, deg, dinv);
  k_scatter<<<2048,  256, 0, stream>>>(ei, ew, dinv, cursor, r2, w2);
  k_gemm1  <<<512,   512, 0, stream>>>(x, Wt, h1p);
  k_reduce <<<3200,  256, 0, stream>>>(h1p, h1b);
  k_agg1   <<<16384, 256, 0, stream>>>(h1b, r2, w2, off, dinv, b1, W2, g);
  k_agg2   <<<512,   256, 0, stream>>>(g, r2, w2, off, dinv, b2, out);
}

// Round 15
// 413.357 us; speedup vs baseline: 1.1517x; 1.0148x over previous
//
#include <hip/hip_runtime.h>

#define N_NODES 16384
#define KDIM    16384
#define E_EDGES 524288
#define H1DIM   200
#define H2DIM   8
#define BNP     256     // padded H1

#define BM 128
#define BK 32
#define KSPLIT 4
#define KLEN 4096       // KDIM / KSPLIT
#define NT 128          // KLEN / BK

typedef __attribute__((ext_vector_type(8))) short bf16x8;
typedef __attribute__((ext_vector_type(4))) float fx4;
typedef __attribute__((ext_vector_type(4))) unsigned int ux4;
typedef __attribute__((ext_vector_type(2))) unsigned int ux2;

__device__ __forceinline__ unsigned short f2bf(float f) {
  unsigned int u = __builtin_bit_cast(unsigned int, f);
  return (unsigned short)((u + 0x7FFFu + ((u >> 16) & 1u)) >> 16);  // RNE
}
__device__ __forceinline__ unsigned int pk2(float a, float b) {
  return (unsigned int)f2bf(a) | ((unsigned int)f2bf(b) << 16);
}
__device__ __forceinline__ float bf2f(unsigned int u) {
  return __builtin_bit_cast(float, u << 16);
}

// ---------------- W1 pack (coalesced, R13-proven) + edge-degree atomics (fused) ----------------
// deg/cnt are memset-zeroed before this kernel; self-loop +1 is folded into k_scan.

__global__ void k_packdeg(const float* __restrict__ W1, unsigned short* __restrict__ Wt,
                          const int* __restrict__ ei, const float* __restrict__ ew,
                          float* deg, int* cnt) {
  int n = threadIdx.x;            // 0..255
  int k8 = blockIdx.x;            // 0..2047
  // --- edge part: thread handles edge e (524288 threads exactly) ---
  int e = k8 * 256 + n;
  int c = ei[E_EDGES + e];
  atomicAdd(&deg[c], ew[e]);
  atomicAdd(&cnt[c], 1);
  // --- pack part ---
  unsigned short v[8];
  if (n < H1DIM) {
    const float* base = W1 + (size_t)(k8 * 8) * H1DIM + n;
#pragma unroll
    for (int i = 0; i < 8; ++i) v[i] = f2bf(base[(size_t)i * H1DIM]);
  } else {
#pragma unroll
    for (int i = 0; i < 8; ++i) v[i] = 0;
  }
  ux4 o;
  o[0] = (unsigned int)v[0] | ((unsigned int)v[1] << 16);
  o[1] = (unsigned int)v[2] | ((unsigned int)v[3] << 16);
  o[2] = (unsigned int)v[4] | ((unsigned int)v[5] << 16);
  o[3] = (unsigned int)v[6] | ((unsigned int)v[7] << 16);
  *(ux4*)(Wt + (size_t)k8 * 2048 + n * 8) = o;
}

// scan over cnt -> off/cursor; dinv = rsqrt(deg + 1) (self-loop weight 1.0 folded here)
__global__ void k_scan(const int* __restrict__ cnt, int* __restrict__ off,
                       int* __restrict__ cursor, const float* __restrict__ deg,
                       float* __restrict__ dinv) {
  __shared__ int s[1024];
  int t = threadIdx.x;
  int base = t * 16;
#pragma unroll
  for (int i = 0; i < 16; ++i) dinv[base + i] = rsqrtf(deg[base + i] + 1.0f);
  int loc[16]; int sum = 0;
#pragma unroll
  for (int i = 0; i < 16; ++i) { loc[i] = cnt[base + i]; sum += loc[i]; }
  s[t] = sum; __syncthreads();
  for (int d = 1; d < 1024; d <<= 1) {
    int v = (t >= d) ? s[t - d] : 0;
    __syncthreads();
    s[t] += v;
    __syncthreads();
  }
  int run = (t == 0) ? 0 : s[t - 1];
#pragma unroll
  for (int i = 0; i < 16; ++i) { off[base + i] = run; cursor[base + i] = run; run += loc[i]; }
  if (t == 1023) off[N_NODES] = run;
}

__global__ void k_scatter(const int* __restrict__ ei, const float* __restrict__ ew,
                          const float* __restrict__ dinv, int* cursor,
                          int* __restrict__ r2, float* __restrict__ w2) {
  int e = blockIdx.x * 256 + threadIdx.x;
  if (e < E_EDGES) {
    int r = ei[e], c = ei[E_EDGES + e];
    float w = dinv[r] * ew[e] * dinv[c];
    int p = atomicAdd(&cursor[c], 1);
    r2[p] = r; w2[p] = w;
  }
}

// ---------------- GEMM1 (R10/R13 verbatim, verified) ----------------

#define LOADA(KT, AI)                                   \
  { const float* _p = xp0 + (KT) * BK;                  \
    aR[AI][0] = *(const fx4*)_p;                        \
    aR[AI][1] = *(const fx4*)(_p + 4); }

#define STAGEB(BUF, KT)                                                                  \
  { const unsigned short* _s = wbase + (size_t)(KT) * 8192 + (size_t)t * 8;              \
    char* _d = ldsB + (BUF) * 16384 + wv * 1024;                                         \
    __builtin_amdgcn_global_load_lds((const __attribute__((address_space(1))) void*)(_s),        (__attribute__((address_space(3))) void*)(_d),        16, 0, 0); \
    __builtin_amdgcn_global_load_lds((const __attribute__((address_space(1))) void*)(_s + 4096), (__attribute__((address_space(3))) void*)(_d + 8192), 16, 0, 0); }

#define WRITEA(AI)                                          \
  { ux4 _dv;                                                \
    _dv[0] = pk2(aR[AI][0][0], aR[AI][0][1]);               \
    _dv[1] = pk2(aR[AI][0][2], aR[AI][0][3]);               \
    _dv[2] = pk2(aR[AI][1][0], aR[AI][1][1]);               \
    _dv[3] = pk2(aR[AI][1][2], aR[AI][1][3]);               \
    *(ux4*)(ldsA + (AI) * 8192 + ((akblk * 128 + am) << 4)) = _dv; }

#define COMPUTE(BUF)                                                                     \
  { const char* _pa = ldsA + (BUF) * 8192;                                               \
    const char* _pb = ldsB + (BUF) * 16384;                                              \
    bf16x8 _af[4], _bf[4];                                                               \
    _Pragma("unroll")                                                                    \
    for (int mi = 0; mi < 4; ++mi)                                                       \
      _af[mi] = *(const bf16x8*)(_pa + ((g * 128 + wm * 64 + mi * 16 + l15) << 4));      \
    _Pragma("unroll")                                                                    \
    for (int ni = 0; ni < 4; ++ni)                                                       \
      _bf[ni] = *(const bf16x8*)(_pb + ((g * 256 + wn * 64 + ni * 16 + l15) << 4));      \
    _Pragma("unroll")                                                                    \
    for (int mi = 0; mi < 4; ++mi)                                                       \
      _Pragma("unroll")                                                                  \
      for (int ni = 0; ni < 4; ++ni)                                                     \
        acc[mi][ni] = __builtin_amdgcn_mfma_f32_16x16x32_bf16(_af[mi], _bf[ni], acc[mi][ni], 0, 0, 0); }

#define SYNC_VM(N)                                          \
  __builtin_amdgcn_sched_barrier(0);                        \
  asm volatile("s_waitcnt vmcnt(" #N ")" ::: "memory");     \
  asm volatile("s_waitcnt lgkmcnt(0)" ::: "memory");        \
  __builtin_amdgcn_s_barrier();                             \
  __builtin_amdgcn_sched_barrier(0);

#define GSTEP(KT, PAR)                 \
  STAGEB((PAR) ^ 1, (KT) + 1)          \
  __builtin_amdgcn_sched_barrier(0);   \
  LOADA((KT) + 2, PAR)                 \
  __builtin_amdgcn_sched_barrier(0);   \
  COMPUTE(PAR)                         \
  WRITEA((PAR) ^ 1)                    \
  SYNC_VM(2)

__launch_bounds__(512, 4)
__global__ void k_gemm1(const float* __restrict__ x, const unsigned short* __restrict__ Wt,
                        float* __restrict__ h1p) {
  __shared__ char lds[49152];       // A: [2][8192] @0, B: [2][16384] @16384
  const int t = threadIdx.x;
  const int wv = t >> 6;
  const int wm = wv >> 2, wn = wv & 3;
  const int ln = t & 63;
  const int g = ln >> 4, l15 = ln & 15;
  const int bid = blockIdx.x;
  const int ks = bid & 3;
  const size_t m0 = (size_t)(bid >> 2) * BM;
  const int k0 = ks * KLEN;

  const int am = t >> 2;
  const int akblk = t & 3;
  const float* xp0 = x + (m0 + am) * (size_t)KDIM + k0 + akblk * 8;
  const unsigned short* wbase = Wt + (size_t)k0 * 256;

  char* ldsA = lds;
  char* ldsB = lds + 16384;

  fx4 acc[4][4] = {};
  fx4 aR[2][2];

  LOADA(0, 0)
  LOADA(1, 1)
  STAGEB(0, 0)
  WRITEA(0)
  SYNC_VM(0)

  for (int kt = 0; kt < NT - 2; kt += 2) {
    GSTEP(kt + 0, 0)
    GSTEP(kt + 1, 1)
  }

  STAGEB(1, NT - 1)
  __builtin_amdgcn_sched_barrier(0);
  COMPUTE(0)
  WRITEA(1)
  SYNC_VM(0)
  COMPUTE(1)

  float* outp = h1p + (size_t)ks * ((size_t)N_NODES * BNP);
#pragma unroll
  for (int mi = 0; mi < 4; ++mi)
#pragma unroll
    for (int ni = 0; ni < 4; ++ni)
#pragma unroll
      for (int r = 0; r < 4; ++r)
        outp[(m0 + wm * 64 + mi * 16 + g * 4 + r) * BNP + wn * 64 + ni * 16 + l15] = acc[mi][ni][r];
}

// ---------------- reduce: full-occupancy grid (R14 verbatim) ----------------

__global__ void k_reduce(const float* __restrict__ h1p, unsigned short* __restrict__ h1b) {
  int i = blockIdx.x * 256 + threadIdx.x;   // < 819200 = 16384 rows * 50 col-blocks
  int row = i / 50, cb = i % 50;
  const fx4* a = (const fx4*)h1p;
  size_t idx = (size_t)row * 64 + cb;
  fx4 v = a[idx];
  v += a[idx + 1048576]; v += a[idx + 2097152]; v += a[idx + 3145728];
  ux2 o;
  o[0] = pk2(v[0], v[1]);
  o[1] = pk2(v[2], v[3]);
  *(ux2*)(h1b + (size_t)row * H1DIM + cb * 4) = o;
}

// ---------------- layer-1 agg + bias + relu + layer-2 linear (fused; 8-way gather unroll) ----------------

__global__ void k_agg1(const unsigned short* __restrict__ h1b, const int* __restrict__ r2,
                       const float* __restrict__ w2, const int* __restrict__ off,
                       const float* __restrict__ dinv, const float* __restrict__ b1,
                       const float* __restrict__ W2, float* __restrict__ g) {
  __shared__ float sh[H1DIM];
  __shared__ float w2s[H1DIM * H2DIM];
  __shared__ float red[256];
  int c = blockIdx.x;
  int t = threadIdx.x;
  if (t < H1DIM) {
    int p0 = off[c], p1 = off[c + 1];
    float acc = 0.0f;
    int p = p0;
    for (; p + 8 <= p1; p += 8) {       // 8-way unroll: 8 row-gathers in flight
      float a0 = 0.f, a1 = 0.f;
#pragma unroll
      for (int u = 0; u < 8; ++u) {
        int rr = r2[p + u];
        float ww = w2[p + u];
        float vv = bf2f((unsigned int)h1b[(size_t)rr * H1DIM + t]);
        if (u & 1) a1 += ww * vv; else a0 += ww * vv;
      }
      acc += a0 + a1;
    }
    for (; p < p1; ++p)
      acc += w2[p] * bf2f((unsigned int)h1b[(size_t)r2[p] * H1DIM + t]);
    float d = dinv[c];
    acc += d * d * bf2f((unsigned int)h1b[(size_t)c * H1DIM + t]);
    sh[t] = fmaxf(acc + b1[t], 0.0f);
  } else {
    for (int i = t - H1DIM; i < H1DIM * H2DIM; i += 256 - H1DIM) w2s[i] = W2[i];
  }
  __syncthreads();
  int jo = t & 7, kc = t >> 3;
  float part = 0.0f;
  for (int k = kc; k < H1DIM; k += 32) part += sh[k] * w2s[k * 8 + jo];
  red[t] = part;
  __syncthreads();
#pragma unroll
  for (int s = 16; s >= 1; s >>= 1) {
    if (kc < s) red[t] += red[t + s * 8];
    __syncthreads();
  }
  if (t < 8) g[(size_t)c * 8 + t] = red[t];
}

// ---------------- layer-2 aggregation + bias (R5 verbatim) ----------------

__global__ void k_agg2(const float* __restrict__ g, const int* __restrict__ r2,
                       const float* __restrict__ w2, const int* __restrict__ off,
                       const float* __restrict__ dinv, const float* __restrict__ b2,
                       float* __restrict__ out) {
  int t = threadIdx.x;
  int c = blockIdx.x * 32 + (t >> 3), j = t & 7;
  int p0 = off[c], p1 = off[c + 1];
  float acc = 0.0f;
  for (int p = p0; p < p1; ++p) acc += w2[p] * g[(size_t)r2[p] * 8 + j];
  float d = dinv[c];
  out[(size_t)c * 8 + j] = acc + d * d * g[(size_t)c * 8 + j] + b2[j];
}

// ---------------- launch ----------------

extern "C" void kernel_launch(void* const* d_in, const int* in_sizes, int n_in,
                              void* d_out, int out_size, void* d_ws, size_t ws_size,
                              hipStream_t stream) {
  (void)in_sizes; (void)n_in; (void)out_size; (void)ws_size;
  const float* x  = (const float*)d_in[0];
  const int*   ei = (const int*)d_in[1];
  const float* ew = (const float*)d_in[2];
  const float* W1 = (const float*)d_in[3];
  const float* b1 = (const float*)d_in[4];
  const float* W2 = (const float*)d_in[5];
  const float* b2 = (const float*)d_in[6];
  float* out = (float*)d_out;
  char* ws = (char*)d_ws;

  float* deg    = (float*)(ws + 0);          // 64 KiB  } contiguous 128 KiB,
  int*   cnt    = (int*)  (ws + 65536);      // 64 KiB  } zeroed by one memset
  float* dinv   = (float*)(ws + 131072);     // 64 KiB
  int*   off    = (int*)  (ws + 196608);     // 16385 ints
  int*   cursor = (int*)  (ws + 262400);     // 64 KiB
  int*   r2     = (int*)  (ws + 327936);     // 2 MiB
  float* w2     = (float*)(ws + 2425088);    // 2 MiB
  unsigned short* Wt = (unsigned short*)(ws + 4522240);   // 8 MiB bf16 packed
  float* h1p    = (float*)(ws + 12910848);   // 4 * [16384][256] f32 = 64 MiB
  float* g      = (float*)(ws + 93126912);   // [16384][8] f32
  unsigned short* h1b = (unsigned short*)(ws + 93651200); // [16384][200] bf16 = 6.55 MiB

  hipMemsetAsync(ws, 0, 131072, stream);     // deg + cnt = 0
  k_packdeg<<<2048,  256, 0, stream>>>(W1, Wt, ei, ew, deg, cnt);
  k_scan   <<<1,    1024, 0, stream>>>(cnt, off, cursor, deg, dinv);
  k_scatter<<<2048,  256, 0, stream>>>(ei, ew, dinv, cursor, r2, w2);
  k_gemm1  <<<512,   512, 0, stream>>>(x, Wt, h1p);
  k_reduce <<<3200,  256, 0, stream>>>(h1p, h1b);
  k_agg1   <<<16384, 256, 0, stream>>>(h1b, r2, w2, off, dinv, b1, W2, g);
  k_agg2   <<<512,   256, 0, stream>>>(g, r2, w2, off, dinv, b2, out);
}

// Round 16
// 402.881 us; speedup vs baseline: 1.1816x; 1.0260x over previous
//
#include <hip/hip_runtime.h>

#define N_NODES 16384
#define KDIM    16384
#define E_EDGES 524288
#define H1DIM   200
#define H2DIM   8

#define BM 128
#define BK 32
#define KSPLIT 4
#define KLEN 4096       // KDIM / KSPLIT
#define NT 128          // KLEN / BK
#define H1P_STRIDE (N_NODES * H1DIM)   // floats per K-split partial (compact, no pad)

typedef __attribute__((ext_vector_type(8))) short bf16x8;
typedef __attribute__((ext_vector_type(4))) float fx4;
typedef __attribute__((ext_vector_type(4))) unsigned int ux4;
typedef __attribute__((ext_vector_type(2))) unsigned int ux2;

__device__ __forceinline__ unsigned short f2bf(float f) {
  unsigned int u = __builtin_bit_cast(unsigned int, f);
  return (unsigned short)((u + 0x7FFFu + ((u >> 16) & 1u)) >> 16);  // RNE
}
__device__ __forceinline__ unsigned int pk2(float a, float b) {
  return (unsigned int)f2bf(a) | ((unsigned int)f2bf(b) << 16);
}
__device__ __forceinline__ float bf2f(unsigned int u) {
  return __builtin_bit_cast(float, u << 16);
}

// ---------------- W1 pack (coalesced) + edge-degree atomics (fused, R15 verbatim) ----------------

__global__ void k_packdeg(const float* __restrict__ W1, unsigned short* __restrict__ Wt,
                          const int* __restrict__ ei, const float* __restrict__ ew,
                          float* deg, int* cnt) {
  int n = threadIdx.x;            // 0..255
  int k8 = blockIdx.x;            // 0..2047
  int e = k8 * 256 + n;
  int c = ei[E_EDGES + e];
  atomicAdd(&deg[c], ew[e]);
  atomicAdd(&cnt[c], 1);
  unsigned short v[8];
  if (n < H1DIM) {
    const float* base = W1 + (size_t)(k8 * 8) * H1DIM + n;
#pragma unroll
    for (int i = 0; i < 8; ++i) v[i] = f2bf(base[(size_t)i * H1DIM]);
  } else {
#pragma unroll
    for (int i = 0; i < 8; ++i) v[i] = 0;
  }
  ux4 o;
  o[0] = (unsigned int)v[0] | ((unsigned int)v[1] << 16);
  o[1] = (unsigned int)v[2] | ((unsigned int)v[3] << 16);
  o[2] = (unsigned int)v[4] | ((unsigned int)v[5] << 16);
  o[3] = (unsigned int)v[6] | ((unsigned int)v[7] << 16);
  *(ux4*)(Wt + (size_t)k8 * 2048 + n * 8) = o;
}

// scan over cnt -> off/cursor (dinv array eliminated; rsqrt computed inline at use sites)
__global__ void k_scan(const int* __restrict__ cnt, int* __restrict__ off,
                       int* __restrict__ cursor) {
  __shared__ int s[1024];
  int t = threadIdx.x;
  int base = t * 16;
  int loc[16]; int sum = 0;
#pragma unroll
  for (int i = 0; i < 16; ++i) { loc[i] = cnt[base + i]; sum += loc[i]; }
  s[t] = sum; __syncthreads();
  for (int d = 1; d < 1024; d <<= 1) {
    int v = (t >= d) ? s[t - d] : 0;
    __syncthreads();
    s[t] += v;
    __syncthreads();
  }
  int run = (t == 0) ? 0 : s[t - 1];
#pragma unroll
  for (int i = 0; i < 16; ++i) { off[base + i] = run; cursor[base + i] = run; run += loc[i]; }
  if (t == 1023) off[N_NODES] = run;
}

__global__ void k_scatter(const int* __restrict__ ei, const float* __restrict__ ew,
                          const float* __restrict__ deg, int* cursor,
                          int* __restrict__ r2, float* __restrict__ w2) {
  int e = blockIdx.x * 256 + threadIdx.x;
  if (e < E_EDGES) {
    int r = ei[e], c = ei[E_EDGES + e];
    float w = rsqrtf(deg[r] + 1.0f) * ew[e] * rsqrtf(deg[c] + 1.0f);
    int p = atomicAdd(&cursor[c], 1);
    r2[p] = r; w2[p] = w;
  }
}

// ---------------- GEMM1 (R10/R13 schedule verbatim; compact 200-col C-write) ----------------

#define LOADA(KT, AI)                                   \
  { const float* _p = xp0 + (KT) * BK;                  \
    aR[AI][0] = *(const fx4*)_p;                        \
    aR[AI][1] = *(const fx4*)(_p + 4); }

#define STAGEB(BUF, KT)                                                                  \
  { const unsigned short* _s = wbase + (size_t)(KT) * 8192 + (size_t)t * 8;              \
    char* _d = ldsB + (BUF) * 16384 + wv * 1024;                                         \
    __builtin_amdgcn_global_load_lds((const __attribute__((address_space(1))) void*)(_s),        (__attribute__((address_space(3))) void*)(_d),        16, 0, 0); \
    __builtin_amdgcn_global_load_lds((const __attribute__((address_space(1))) void*)(_s + 4096), (__attribute__((address_space(3))) void*)(_d + 8192), 16, 0, 0); }

#define WRITEA(AI)                                          \
  { ux4 _dv;                                                \
    _dv[0] = pk2(aR[AI][0][0], aR[AI][0][1]);               \
    _dv[1] = pk2(aR[AI][0][2], aR[AI][0][3]);               \
    _dv[2] = pk2(aR[AI][1][0], aR[AI][1][1]);               \
    _dv[3] = pk2(aR[AI][1][2], aR[AI][1][3]);               \
    *(ux4*)(ldsA + (AI) * 8192 + ((akblk * 128 + am) << 4)) = _dv; }

#define COMPUTE(BUF)                                                                     \
  { const char* _pa = ldsA + (BUF) * 8192;                                               \
    const char* _pb = ldsB + (BUF) * 16384;                                              \
    bf16x8 _af[4], _bf[4];                                                               \
    _Pragma("unroll")                                                                    \
    for (int mi = 0; mi < 4; ++mi)                                                       \
      _af[mi] = *(const bf16x8*)(_pa + ((g * 128 + wm * 64 + mi * 16 + l15) << 4));      \
    _Pragma("unroll")                                                                    \
    for (int ni = 0; ni < 4; ++ni)                                                       \
      _bf[ni] = *(const bf16x8*)(_pb + ((g * 256 + wn * 64 + ni * 16 + l15) << 4));      \
    _Pragma("unroll")                                                                    \
    for (int mi = 0; mi < 4; ++mi)                                                       \
      _Pragma("unroll")                                                                  \
      for (int ni = 0; ni < 4; ++ni)                                                     \
        acc[mi][ni] = __builtin_amdgcn_mfma_f32_16x16x32_bf16(_af[mi], _bf[ni], acc[mi][ni], 0, 0, 0); }

#define SYNC_VM(N)                                          \
  __builtin_amdgcn_sched_barrier(0);                        \
  asm volatile("s_waitcnt vmcnt(" #N ")" ::: "memory");     \
  asm volatile("s_waitcnt lgkmcnt(0)" ::: "memory");        \
  __builtin_amdgcn_s_barrier();                             \
  __builtin_amdgcn_sched_barrier(0);

#define GSTEP(KT, PAR)                 \
  STAGEB((PAR) ^ 1, (KT) + 1)          \
  __builtin_amdgcn_sched_barrier(0);   \
  LOADA((KT) + 2, PAR)                 \
  __builtin_amdgcn_sched_barrier(0);   \
  COMPUTE(PAR)                         \
  WRITEA((PAR) ^ 1)                    \
  SYNC_VM(2)

__launch_bounds__(512, 4)
__global__ void k_gemm1(const float* __restrict__ x, const unsigned short* __restrict__ Wt,
                        float* __restrict__ h1p) {
  __shared__ char lds[49152];       // A: [2][8192] @0, B: [2][16384] @16384
  const int t = threadIdx.x;
  const int wv = t >> 6;
  const int wm = wv >> 2, wn = wv & 3;
  const int ln = t & 63;
  const int g = ln >> 4, l15 = ln & 15;
  const int bid = blockIdx.x;
  const int ks = bid & 3;
  const size_t m0 = (size_t)(bid >> 2) * BM;
  const int k0 = ks * KLEN;

  const int am = t >> 2;
  const int akblk = t & 3;
  const float* xp0 = x + (m0 + am) * (size_t)KDIM + k0 + akblk * 8;
  const unsigned short* wbase = Wt + (size_t)k0 * 256;

  char* ldsA = lds;
  char* ldsB = lds + 16384;

  fx4 acc[4][4] = {};
  fx4 aR[2][2];

  LOADA(0, 0)
  LOADA(1, 1)
  STAGEB(0, 0)
  WRITEA(0)
  SYNC_VM(0)

  for (int kt = 0; kt < NT - 2; kt += 2) {
    GSTEP(kt + 0, 0)
    GSTEP(kt + 1, 1)
  }

  STAGEB(1, NT - 1)
  __builtin_amdgcn_sched_barrier(0);
  COMPUTE(0)
  WRITEA(1)
  SYNC_VM(0)
  COMPUTE(1)

  // compact C-write: only cols < 200 (pad cols 200..255 never materialized)
  float* outp = h1p + (size_t)ks * H1P_STRIDE;
#pragma unroll
  for (int mi = 0; mi < 4; ++mi)
#pragma unroll
    for (int ni = 0; ni < 4; ++ni) {
      int col = wn * 64 + ni * 16 + l15;
      if (col < H1DIM) {
#pragma unroll
        for (int r = 0; r < 4; ++r)
          outp[(m0 + wm * 64 + mi * 16 + g * 4 + r) * H1DIM + col] = acc[mi][ni][r];
      }
    }
}

// ---------------- reduce: pure linear stream over compact [4][16384][200] ----------------

__global__ void k_reduce(const float* __restrict__ h1p, unsigned short* __restrict__ h1b) {
  int i = blockIdx.x * 256 + threadIdx.x;   // < 819200 fx4 items
  const fx4* a = (const fx4*)h1p;
  fx4 v = a[i];
  v += a[i + 819200]; v += a[i + 1638400]; v += a[i + 2457600];
  ux2 o;
  o[0] = pk2(v[0], v[1]);
  o[1] = pk2(v[2], v[3]);
  *(ux2*)(h1b + (size_t)i * 4) = o;
}

// ---------------- layer-1 agg + bias + relu + layer-2 linear (fused; 8-way unroll) ----------------

__global__ void k_agg1(const unsigned short* __restrict__ h1b, const int* __restrict__ r2,
                       const float* __restrict__ w2, const int* __restrict__ off,
                       const float* __restrict__ deg, const float* __restrict__ b1,
                       const float* __restrict__ W2, float* __restrict__ g) {
  __shared__ float sh[H1DIM];
  __shared__ float w2s[H1DIM * H2DIM];
  __shared__ float red[256];
  int c = blockIdx.x;
  int t = threadIdx.x;
  if (t < H1DIM) {
    int p0 = off[c], p1 = off[c + 1];
    float acc = 0.0f;
    int p = p0;
    for (; p + 8 <= p1; p += 8) {       // 8-way unroll: 8 row-gathers in flight
      float a0 = 0.f, a1 = 0.f;
#pragma unroll
      for (int u = 0; u < 8; ++u) {
        int rr = r2[p + u];
        float ww = w2[p + u];
        float vv = bf2f((unsigned int)h1b[(size_t)rr * H1DIM + t]);
        if (u & 1) a1 += ww * vv; else a0 += ww * vv;
      }
      acc += a0 + a1;
    }
    for (; p < p1; ++p)
      acc += w2[p] * bf2f((unsigned int)h1b[(size_t)r2[p] * H1DIM + t]);
    float d2 = 1.0f / (deg[c] + 1.0f);    // dinv^2 exactly
    acc += d2 * bf2f((unsigned int)h1b[(size_t)c * H1DIM + t]);
    sh[t] = fmaxf(acc + b1[t], 0.0f);
  } else {
    for (int i = t - H1DIM; i < H1DIM * H2DIM; i += 256 - H1DIM) w2s[i] = W2[i];
  }
  __syncthreads();
  int jo = t & 7, kc = t >> 3;
  float part = 0.0f;
  for (int k = kc; k < H1DIM; k += 32) part += sh[k] * w2s[k * 8 + jo];
  red[t] = part;
  __syncthreads();
#pragma unroll
  for (int s = 16; s >= 1; s >>= 1) {
    if (kc < s) red[t] += red[t + s * 8];
    __syncthreads();
  }
  if (t < 8) g[(size_t)c * 8 + t] = red[t];
}

// ---------------- layer-2 aggregation + bias ----------------

__global__ void k_agg2(const float* __restrict__ g, const int* __restrict__ r2,
                       const float* __restrict__ w2, const int* __restrict__ off,
                       const float* __restrict__ deg, const float* __restrict__ b2,
                       float* __restrict__ out) {
  int t = threadIdx.x;
  int c = blockIdx.x * 32 + (t >> 3), j = t & 7;
  int p0 = off[c], p1 = off[c + 1];
  float acc = 0.0f;
  for (int p = p0; p < p1; ++p) acc += w2[p] * g[(size_t)r2[p] * 8 + j];
  float d2 = 1.0f / (deg[c] + 1.0f);
  out[(size_t)c * 8 + j] = acc + d2 * g[(size_t)c * 8 + j] + b2[j];
}

// ---------------- launch ----------------

extern "C" void kernel_launch(void* const* d_in, const int* in_sizes, int n_in,
                              void* d_out, int out_size, void* d_ws, size_t ws_size,
                              hipStream_t stream) {
  (void)in_sizes; (void)n_in; (void)out_size; (void)ws_size;
  const float* x  = (const float*)d_in[0];
  const int*   ei = (const int*)d_in[1];
  const float* ew = (const float*)d_in[2];
  const float* W1 = (const float*)d_in[3];
  const float* b1 = (const float*)d_in[4];
  const float* W2 = (const float*)d_in[5];
  const float* b2 = (const float*)d_in[6];
  float* out = (float*)d_out;
  char* ws = (char*)d_ws;

  float* deg    = (float*)(ws + 0);          // 64 KiB  } contiguous 128 KiB,
  int*   cnt    = (int*)  (ws + 65536);      // 64 KiB  } zeroed by one memset
  int*   off    = (int*)  (ws + 196608);     // 16385 ints
  int*   cursor = (int*)  (ws + 262400);     // 64 KiB
  int*   r2     = (int*)  (ws + 327936);     // 2 MiB
  float* w2     = (float*)(ws + 2425088);    // 2 MiB
  unsigned short* Wt = (unsigned short*)(ws + 4522240);   // 8 MiB bf16 packed
  float* h1p    = (float*)(ws + 12910848);   // 4 * [16384][200] f32 = 52.4 MiB
  float* g      = (float*)(ws + 93126912);   // [16384][8] f32
  unsigned short* h1b = (unsigned short*)(ws + 93651200); // [16384][200] bf16 = 6.55 MiB

  hipMemsetAsync(ws, 0, 131072, stream);     // deg + cnt = 0
  k_packdeg<<<2048,  256, 0, stream>>>(W1, Wt, ei, ew, deg, cnt);
  k_scan   <<<1,    1024, 0, stream>>>(cnt, off, cursor);
  k_scatter<<<2048,  256, 0, stream>>>(ei, ew, deg, cursor, r2, w2);
  k_gemm1  <<<512,   512, 0, stream>>>(x, Wt, h1p);
  k_reduce <<<3200,  256, 0, stream>>>(h1p, h1b);
  k_agg1   <<<16384, 256, 0, stream>>>(h1b, r2, w2, off, deg, b1, W2, g);
  k_agg2   <<<512,   256, 0, stream>>>(g, r2, w2, off, deg, b2, out);
}

// Round 17
// 381.703 us; speedup vs baseline: 1.2472x; 1.0555x over previous
//
#include <hip/hip_runtime.h>

#define N_NODES 16384
#define KDIM    16384
#define E_EDGES 524288
#define H1DIM   200
#define H2DIM   8

#define BM 128
#define BK 32
#define KSPLIT 4
#define KLEN 4096       // KDIM / KSPLIT
#define NT 128          // KLEN / BK
#define H1P_STRIDE (N_NODES * H1DIM)   // floats per K-split partial (compact, no pad)

typedef __attribute__((ext_vector_type(8))) short bf16x8;
typedef __attribute__((ext_vector_type(4))) float fx4;
typedef __attribute__((ext_vector_type(4))) unsigned int ux4;
typedef __attribute__((ext_vector_type(2))) unsigned int ux2;

__device__ __forceinline__ unsigned short f2bf(float f) {
  unsigned int u = __builtin_bit_cast(unsigned int, f);
  return (unsigned short)((u + 0x7FFFu + ((u >> 16) & 1u)) >> 16);  // RNE
}
__device__ __forceinline__ unsigned int pk2(float a, float b) {
  return (unsigned int)f2bf(a) | ((unsigned int)f2bf(b) << 16);
}
__device__ __forceinline__ float bf2f(unsigned int u) {
  return __builtin_bit_cast(float, u << 16);
}

// ---------------- W1 pack (coalesced) + edge-degree atomics + per-edge rank ----------------
// deg/cnt memset-zeroed before this kernel; self-loop +1 folded into rsqrt(deg+1) at use.
// rank[e] = this edge's unique slot index within its destination node's CSR segment
// (the atomicAdd return value) -> k_scatter needs NO atomics.

__global__ void k_packdeg(const float* __restrict__ W1, unsigned short* __restrict__ Wt,
                          const int* __restrict__ ei, const float* __restrict__ ew,
                          float* deg, int* cnt, int* __restrict__ rank) {
  int n = threadIdx.x;            // 0..255
  int k8 = blockIdx.x;            // 0..2047
  int e = k8 * 256 + n;
  int c = ei[E_EDGES + e];
  rank[e] = atomicAdd(&cnt[c], 1);
  atomicAdd(&deg[c], ew[e]);
  unsigned short v[8];
  if (n < H1DIM) {
    const float* base = W1 + (size_t)(k8 * 8) * H1DIM + n;
#pragma unroll
    for (int i = 0; i < 8; ++i) v[i] = f2bf(base[(size_t)i * H1DIM]);
  } else {
#pragma unroll
    for (int i = 0; i < 8; ++i) v[i] = 0;
  }
  ux4 o;
  o[0] = (unsigned int)v[0] | ((unsigned int)v[1] << 16);
  o[1] = (unsigned int)v[2] | ((unsigned int)v[3] << 16);
  o[2] = (unsigned int)v[4] | ((unsigned int)v[5] << 16);
  o[3] = (unsigned int)v[6] | ((unsigned int)v[7] << 16);
  *(ux4*)(Wt + (size_t)k8 * 2048 + n * 8) = o;
}

// scan over cnt -> off (cursor eliminated)
__global__ void k_scan(const int* __restrict__ cnt, int* __restrict__ off) {
  __shared__ int s[1024];
  int t = threadIdx.x;
  int base = t * 16;
  int loc[16]; int sum = 0;
#pragma unroll
  for (int i = 0; i < 16; ++i) { loc[i] = cnt[base + i]; sum += loc[i]; }
  s[t] = sum; __syncthreads();
  for (int d = 1; d < 1024; d <<= 1) {
    int v = (t >= d) ? s[t - d] : 0;
    __syncthreads();
    s[t] += v;
    __syncthreads();
  }
  int run = (t == 0) ? 0 : s[t - 1];
#pragma unroll
  for (int i = 0; i < 16; ++i) { off[base + i] = run; run += loc[i]; }
  if (t == 1023) off[N_NODES] = run;
}

// atomic-free scatter: slot = off[c] + rank[e]
__global__ void k_scatter(const int* __restrict__ ei, const float* __restrict__ ew,
                          const float* __restrict__ deg, const int* __restrict__ off,
                          const int* __restrict__ rank,
                          int* __restrict__ r2, float* __restrict__ w2) {
  int e = blockIdx.x * 256 + threadIdx.x;
  if (e < E_EDGES) {
    int r = ei[e], c = ei[E_EDGES + e];
    float w = rsqrtf(deg[r] + 1.0f) * ew[e] * rsqrtf(deg[c] + 1.0f);
    int p = off[c] + rank[e];
    r2[p] = r; w2[p] = w;
  }
}

// ---------------- GEMM1 (R10/R13 schedule verbatim; compact 200-col C-write) ----------------

#define LOADA(KT, AI)                                   \
  { const float* _p = xp0 + (KT) * BK;                  \
    aR[AI][0] = *(const fx4*)_p;                        \
    aR[AI][1] = *(const fx4*)(_p + 4); }

#define STAGEB(BUF, KT)                                                                  \
  { const unsigned short* _s = wbase + (size_t)(KT) * 8192 + (size_t)t * 8;              \
    char* _d = ldsB + (BUF) * 16384 + wv * 1024;                                         \
    __builtin_amdgcn_global_load_lds((const __attribute__((address_space(1))) void*)(_s),        (__attribute__((address_space(3))) void*)(_d),        16, 0, 0); \
    __builtin_amdgcn_global_load_lds((const __attribute__((address_space(1))) void*)(_s + 4096), (__attribute__((address_space(3))) void*)(_d + 8192), 16, 0, 0); }

#define WRITEA(AI)                                          \
  { ux4 _dv;                                                \
    _dv[0] = pk2(aR[AI][0][0], aR[AI][0][1]);               \
    _dv[1] = pk2(aR[AI][0][2], aR[AI][0][3]);               \
    _dv[2] = pk2(aR[AI][1][0], aR[AI][1][1]);               \
    _dv[3] = pk2(aR[AI][1][2], aR[AI][1][3]);               \
    *(ux4*)(ldsA + (AI) * 8192 + ((akblk * 128 + am) << 4)) = _dv; }

#define COMPUTE(BUF)                                                                     \
  { const char* _pa = ldsA + (BUF) * 8192;                                               \
    const char* _pb = ldsB + (BUF) * 16384;                                              \
    bf16x8 _af[4], _bf[4];                                                               \
    _Pragma("unroll")                                                                    \
    for (int mi = 0; mi < 4; ++mi)                                                       \
      _af[mi] = *(const bf16x8*)(_pa + ((g * 128 + wm * 64 + mi * 16 + l15) << 4));      \
    _Pragma("unroll")                                                                    \
    for (int ni = 0; ni < 4; ++ni)                                                       \
      _bf[ni] = *(const bf16x8*)(_pb + ((g * 256 + wn * 64 + ni * 16 + l15) << 4));      \
    _Pragma("unroll")                                                                    \
    for (int mi = 0; mi < 4; ++mi)                                                       \
      _Pragma("unroll")                                                                  \
      for (int ni = 0; ni < 4; ++ni)                                                     \
        acc[mi][ni] = __builtin_amdgcn_mfma_f32_16x16x32_bf16(_af[mi], _bf[ni], acc[mi][ni], 0, 0, 0); }

#define SYNC_VM(N)                                          \
  __builtin_amdgcn_sched_barrier(0);                        \
  asm volatile("s_waitcnt vmcnt(" #N ")" ::: "memory");     \
  asm volatile("s_waitcnt lgkmcnt(0)" ::: "memory");        \
  __builtin_amdgcn_s_barrier();                             \
  __builtin_amdgcn_sched_barrier(0);

#define GSTEP(KT, PAR)                 \
  STAGEB((PAR) ^ 1, (KT) + 1)          \
  __builtin_amdgcn_sched_barrier(0);   \
  LOADA((KT) + 2, PAR)                 \
  __builtin_amdgcn_sched_barrier(0);   \
  COMPUTE(PAR)                         \
  WRITEA((PAR) ^ 1)                    \
  SYNC_VM(2)

__launch_bounds__(512, 4)
__global__ void k_gemm1(const float* __restrict__ x, const unsigned short* __restrict__ Wt,
                        float* __restrict__ h1p) {
  __shared__ char lds[49152];       // A: [2][8192] @0, B: [2][16384] @16384
  const int t = threadIdx.x;
  const int wv = t >> 6;
  const int wm = wv >> 2, wn = wv & 3;
  const int ln = t & 63;
  const int g = ln >> 4, l15 = ln & 15;
  const int bid = blockIdx.x;
  const int ks = bid & 3;
  const size_t m0 = (size_t)(bid >> 2) * BM;
  const int k0 = ks * KLEN;

  const int am = t >> 2;
  const int akblk = t & 3;
  const float* xp0 = x + (m0 + am) * (size_t)KDIM + k0 + akblk * 8;
  const unsigned short* wbase = Wt + (size_t)k0 * 256;

  char* ldsA = lds;
  char* ldsB = lds + 16384;

  fx4 acc[4][4] = {};
  fx4 aR[2][2];

  LOADA(0, 0)
  LOADA(1, 1)
  STAGEB(0, 0)
  WRITEA(0)
  SYNC_VM(0)

  for (int kt = 0; kt < NT - 2; kt += 2) {
    GSTEP(kt + 0, 0)
    GSTEP(kt + 1, 1)
  }

  STAGEB(1, NT - 1)
  __builtin_amdgcn_sched_barrier(0);
  COMPUTE(0)
  WRITEA(1)
  SYNC_VM(0)
  COMPUTE(1)

  // compact C-write: only cols < 200 (pad cols never materialized)
  float* outp = h1p + (size_t)ks * H1P_STRIDE;
#pragma unroll
  for (int mi = 0; mi < 4; ++mi)
#pragma unroll
    for (int ni = 0; ni < 4; ++ni) {
      int col = wn * 64 + ni * 16 + l15;
      if (col < H1DIM) {
#pragma unroll
        for (int r = 0; r < 4; ++r)
          outp[(m0 + wm * 64 + mi * 16 + g * 4 + r) * H1DIM + col] = acc[mi][ni][r];
      }
    }
}

// ---------------- reduce: pure linear stream over compact [4][16384][200] ----------------

__global__ void k_reduce(const float* __restrict__ h1p, unsigned short* __restrict__ h1b) {
  int i = blockIdx.x * 256 + threadIdx.x;   // < 819200 fx4 items
  const fx4* a = (const fx4*)h1p;
  fx4 v = a[i];
  v += a[i + 819200]; v += a[i + 1638400]; v += a[i + 2457600];
  ux2 o;
  o[0] = pk2(v[0], v[1]);
  o[1] = pk2(v[2], v[3]);
  *(ux2*)(h1b + (size_t)i * 4) = o;
}

// ---------------- layer-1 agg + bias + relu + layer-2 linear (fused; 8-way unroll) ----------------

__global__ void k_agg1(const unsigned short* __restrict__ h1b, const int* __restrict__ r2,
                       const float* __restrict__ w2, const int* __restrict__ off,
                       const float* __restrict__ deg, const float* __restrict__ b1,
                       const float* __restrict__ W2, float* __restrict__ g) {
  __shared__ float sh[H1DIM];
  __shared__ float w2s[H1DIM * H2DIM];
  __shared__ float red[256];
  int c = blockIdx.x;
  int t = threadIdx.x;
  if (t < H1DIM) {
    int p0 = off[c], p1 = off[c + 1];
    float acc = 0.0f;
    int p = p0;
    for (; p + 8 <= p1; p += 8) {       // 8-way unroll: 8 row-gathers in flight
      float a0 = 0.f, a1 = 0.f;
#pragma unroll
      for (int u = 0; u < 8; ++u) {
        int rr = r2[p + u];
        float ww = w2[p + u];
        float vv = bf2f((unsigned int)h1b[(size_t)rr * H1DIM + t]);
        if (u & 1) a1 += ww * vv; else a0 += ww * vv;
      }
      acc += a0 + a1;
    }
    for (; p < p1; ++p)
      acc += w2[p] * bf2f((unsigned int)h1b[(size_t)r2[p] * H1DIM + t]);
    float d2 = 1.0f / (deg[c] + 1.0f);    // dinv^2 exactly
    acc += d2 * bf2f((unsigned int)h1b[(size_t)c * H1DIM + t]);
    sh[t] = fmaxf(acc + b1[t], 0.0f);
  } else {
    for (int i = t - H1DIM; i < H1DIM * H2DIM; i += 256 - H1DIM) w2s[i] = W2[i];
  }
  __syncthreads();
  int jo = t & 7, kc = t >> 3;
  float part = 0.0f;
  for (int k = kc; k < H1DIM; k += 32) part += sh[k] * w2s[k * 8 + jo];
  red[t] = part;
  __syncthreads();
#pragma unroll
  for (int s = 16; s >= 1; s >>= 1) {
    if (kc < s) red[t] += red[t + s * 8];
    __syncthreads();
  }
  if (t < 8) g[(size_t)c * 8 + t] = red[t];
}

// ---------------- layer-2 aggregation + bias ----------------

__global__ void k_agg2(const float* __restrict__ g, const int* __restrict__ r2,
                       const float* __restrict__ w2, const int* __restrict__ off,
                       const float* __restrict__ deg, const float* __restrict__ b2,
                       float* __restrict__ out) {
  int t = threadIdx.x;
  int c = blockIdx.x * 32 + (t >> 3), j = t & 7;
  int p0 = off[c], p1 = off[c + 1];
  float acc = 0.0f;
  for (int p = p0; p < p1; ++p) acc += w2[p] * g[(size_t)r2[p] * 8 + j];
  float d2 = 1.0f / (deg[c] + 1.0f);
  out[(size_t)c * 8 + j] = acc + d2 * g[(size_t)c * 8 + j] + b2[j];
}

// ---------------- launch ----------------

extern "C" void kernel_launch(void* const* d_in, const int* in_sizes, int n_in,
                              void* d_out, int out_size, void* d_ws, size_t ws_size,
                              hipStream_t stream) {
  (void)in_sizes; (void)n_in; (void)out_size; (void)ws_size;
  const float* x  = (const float*)d_in[0];
  const int*   ei = (const int*)d_in[1];
  const float* ew = (const float*)d_in[2];
  const float* W1 = (const float*)d_in[3];
  const float* b1 = (const float*)d_in[4];
  const float* W2 = (const float*)d_in[5];
  const float* b2 = (const float*)d_in[6];
  float* out = (float*)d_out;
  char* ws = (char*)d_ws;

  float* deg    = (float*)(ws + 0);          // 64 KiB  } contiguous 128 KiB,
  int*   cnt    = (int*)  (ws + 65536);      // 64 KiB  } zeroed by one memset
  int*   off    = (int*)  (ws + 196608);     // 16385 ints
  int*   r2     = (int*)  (ws + 327936);     // 2 MiB
  float* w2     = (float*)(ws + 2425088);    // 2 MiB
  unsigned short* Wt = (unsigned short*)(ws + 4522240);   // 8 MiB bf16 packed
  float* h1p    = (float*)(ws + 12910848);   // 4 * [16384][200] f32 = 52.4 MiB (ends ~65.3 MB)
  int*   rank   = (int*)  (ws + 66060288);   // 2 MiB per-edge rank (free region)
  float* g      = (float*)(ws + 93126912);   // [16384][8] f32
  unsigned short* h1b = (unsigned short*)(ws + 93651200); // [16384][200] bf16 = 6.55 MiB

  hipMemsetAsync(ws, 0, 131072, stream);     // deg + cnt = 0
  k_packdeg<<<2048,  256, 0, stream>>>(W1, Wt, ei, ew, deg, cnt, rank);
  k_scan   <<<1,    1024, 0, stream>>>(cnt, off);
  k_scatter<<<2048,  256, 0, stream>>>(ei, ew, deg, off, rank, r2, w2);
  k_gemm1  <<<512,   512, 0, stream>>>(x, Wt, h1p);
  k_reduce <<<3200,  256, 0, stream>>>(h1p, h1b);
  k_agg1   <<<16384, 256, 0, stream>>>(h1b, r2, w2, off, deg, b1, W2, g);
  k_agg2   <<<512,   256, 0, stream>>>(g, r2, w2, off, deg, b2, out);
}